// Round 4
// baseline (486.569 us; speedup 1.0000x reference)
//
#include <hip/hip_runtime.h>
#include <hip/hip_bf16.h>

#define NUM_REAL 19
#define NIMG     4
#define T_TOT    76        // NIMG*NUM_REAL
#define V_SEL    131       // 10000 / 76
#define M_ROWS   9956      // T_TOT*V_SEL
#define MP       9984      // padded to 78*128
#define CDIM     256
#define P_PIX    65536
#define TILE     128
#define BK       32
#define RPI      2489      // rows per image = 19*131
#define NT1      3081      // 78*79/2 upper-triangular tiles
#define NCHUNK   32        // label chunks per image
#define CHPIX    2048      // dom pixels per chunk
#define CT       5         // 128-row tiles per 524-row class block
#define NT2      (NUM_REAL * 15)   // 19 classes * C(5+1,2) upper tiles

typedef __attribute__((ext_vector_type(8))) short short8;
typedef __attribute__((ext_vector_type(4))) float floatx4;

// ---------------- Kernel 1a: per-chunk class histograms ----------------
__global__ __launch_bounds__(256) void k_hist(const int* __restrict__ label,
                                              int* __restrict__ ghist)
{
    __shared__ int h[NUM_REAL];
    const int img = blockIdx.y, ch = blockIdx.x, tid = threadIdx.x;
    if (tid < NUM_REAL) h[tid] = 0;
    __syncthreads();
    const int* lab = label + img * 1048576;
    const int p0 = ch * CHPIX + tid * 8;
    #pragma unroll
    for (int j = 0; j < 8; ++j) {
        int p = p0 + j;
        int c = lab[((p >> 8) << 12) + ((p & 255) << 2)];
        atomicAdd(&h[c], 1);
    }
    __syncthreads();
    if (tid < NUM_REAL) ghist[(img * NCHUNK + ch) * NUM_REAL + tid] = h[tid];
}

// ---------------- Kernel 1b: ordered scatter of first-131 pixels per class ----------------
__global__ __launch_bounds__(256) void k_scatter(const int* __restrict__ label,
                                                 const int* __restrict__ ghist,
                                                 int* __restrict__ sel)
{
    __shared__ int cnt[NUM_REAL * 256];
    const int img = blockIdx.y, ch = blockIdx.x, tid = threadIdx.x;
    #pragma unroll
    for (int k = 0; k < NUM_REAL; ++k) cnt[k * 256 + tid] = 0;
    __shared__ int base[NUM_REAL];
    if (tid < NUM_REAL) {
        int b = 0;
        for (int q = 0; q < ch; ++q) b += ghist[(img * NCHUNK + q) * NUM_REAL + tid];
        base[tid] = b;
    }
    const int* lab = label + img * 1048576;
    const int p0 = ch * CHPIX + tid * 8;
    #pragma unroll
    for (int j = 0; j < 8; ++j) {
        int p = p0 + j;
        int c = lab[((p >> 8) << 12) + ((p & 255) << 2)];
        cnt[c * 256 + tid]++;
    }
    __syncthreads();
    if (tid < NUM_REAL) {                    // exclusive scan over 256 threads, seeded by base
        int run = base[tid], bb = tid * 256;
        for (int t2 = 0; t2 < 256; ++t2) {
            int tmp = cnt[bb + t2];
            cnt[bb + t2] = run;
            run += tmp;
        }
    }
    __syncthreads();
    bool need = false;
    #pragma unroll
    for (int k = 0; k < NUM_REAL; ++k) if (cnt[k * 256 + tid] < V_SEL) need = true;
    if (need) {
        for (int j = 0; j < 8; ++j) {
            int p = p0 + j;
            int c = lab[((p >> 8) << 12) + ((p & 255) << 2)];
            int r = cnt[c * 256 + tid]++;
            if (r < V_SEL) sel[(img * NUM_REAL + c) * V_SEL + r] = p;
        }
    }
}

// ---------------- Kernel 2a: gather -> fp32 Ftmp + norm atomics ----------------
__global__ __launch_bounds__(256) void k_gather1(const float* __restrict__ feats,
                                                 const int* __restrict__ sel,
                                                 float* __restrict__ Ftmp,
                                                 float* __restrict__ nrm)
{
    __shared__ int pbuf[RPI];
    const int b  = blockIdx.y;
    const int c0 = blockIdx.x * 4;
    const int tid = threadIdx.x;
    for (int s = tid; s < RPI; s += 256) pbuf[s] = sel[b * RPI + s];
    __syncthreads();
    const float* f0 = feats + (size_t)(b * CDIM + c0) * P_PIX;
    const int NIT = (RPI + 255) / 256;       // 10
    const int rot = blockIdx.x % NIT;        // de-lockstep blocks sharing rows
    for (int s = 0; s < NIT; ++s) {
        int r = ((s + rot) % NIT) * 256 + tid;
        if (r >= RPI) continue;
        int p = pbuf[r];
        float x0 = f0[p];
        float x1 = f0[p + P_PIX];
        float x2 = f0[p + 2 * P_PIX];
        float x3 = f0[p + 3 * P_PIX];
        int row = b * RPI + r;
        float4 v = make_float4(x0, x1, x2, x3);
        *reinterpret_cast<float4*>(Ftmp + (size_t)row * CDIM + c0) = v;
        atomicAdd(&nrm[row], x0 * x0 + x1 * x1 + x2 * x2 + x3 * x3);
    }
}

// ---------------- Kernel 2b: normalize -> bf16 F[MP][256] ----------------
__global__ __launch_bounds__(256) void k_gather2(const float* __restrict__ Ftmp,
                                                 const float* __restrict__ nrm,
                                                 unsigned short* __restrict__ F)
{
    const int row = blockIdx.x * 4 + (threadIdx.x >> 6);
    const int c4  = (threadIdx.x & 63) * 4;
    ushort4 o;
    if (row < M_ROWS) {
        float4 v = *reinterpret_cast<const float4*>(Ftmp + (size_t)row * CDIM + c4);
        float rinv = 1.0f / fmaxf(sqrtf(nrm[row]), 1e-12f);
        __hip_bfloat16 h0 = __float2bfloat16(v.x * rinv);
        __hip_bfloat16 h1 = __float2bfloat16(v.y * rinv);
        __hip_bfloat16 h2 = __float2bfloat16(v.z * rinv);
        __hip_bfloat16 h3 = __float2bfloat16(v.w * rinv);
        o.x = *reinterpret_cast<unsigned short*>(&h0);
        o.y = *reinterpret_cast<unsigned short*>(&h1);
        o.z = *reinterpret_cast<unsigned short*>(&h2);
        o.w = *reinterpret_cast<unsigned short*>(&h3);
    } else {
        o.x = o.y = o.z = o.w = 0;
    }
    *reinterpret_cast<ushort4*>(F + (size_t)row * CDIM + c4) = o;
}

// ---------------- Kernel 3: LDS-free symmetric Gram; frags straight from global ----------------
// Per wave, frag rows are 16 consecutive F rows; lanes (lr,qr) cover 16 full 64B lines
// per dwordx4 -> perfectly coalesced. No __syncthreads in K-loop: compiler emits
// fine-grained s_waitcnt vmcnt(N) (the AITER pattern), no barrier drain.
__global__ __launch_bounds__(256) void k_gemm(const unsigned short* __restrict__ F,
                                              float* __restrict__ negsum)
{
    __shared__ float red[TILE * 2];
    __shared__ float cred[TILE * 2];

    int t = blockIdx.x;                      // upper-triangular tile decode
    int bi = (int)((157.0f - sqrtf(24649.0f - 8.0f * (float)t)) * 0.5f);
    if (bi < 0) bi = 0;
    if (bi > 77) bi = 77;
    while ((bi + 1) * 78 - ((bi + 1) * bi) / 2 <= t) ++bi;
    while (bi * 78 - (bi * (bi - 1)) / 2 > t) --bi;
    int bj = bi + (t - (bi * 78 - (bi * (bi - 1)) / 2));
    const bool diag = (bi == bj);
    const int i0 = bi * TILE, j0 = bj * TILE;

    const int tid  = threadIdx.x;
    const int wave = tid >> 6, lane = tid & 63;
    const int qr = lane >> 4, lr = lane & 15;
    const int wr = (wave >> 1) * 64, wc = (wave & 1) * 64;

    floatx4 acc[4][4];
    floatx4 zero4 = {0.f, 0.f, 0.f, 0.f};
    #pragma unroll
    for (int a = 0; a < 4; ++a)
        #pragma unroll
        for (int b = 0; b < 4; ++b) acc[a][b] = zero4;

    // frag base pointers (short8 units). mi stride: 16 rows * 256 shorts = 512 units.
    const short8* pA = reinterpret_cast<const short8*>(F + (size_t)(i0 + wr + lr) * CDIM) + qr;
    const short8* pB = reinterpret_cast<const short8*>(F + (size_t)(j0 + wc + lr) * CDIM) + qr;

    short8 a[2][4], b[2][4];
    #pragma unroll
    for (int mi = 0; mi < 4; ++mi) a[0][mi] = pA[mi * 512];
    #pragma unroll
    for (int ni = 0; ni < 4; ++ni) b[0][ni] = pB[ni * 512];

    #pragma unroll
    for (int k = 0; k < 8; ++k) {            // chunk = 32 K-elems = 4 short8 units
        const int cur = k & 1, nxt = cur ^ 1;
        if (k < 7) {
            #pragma unroll
            for (int mi = 0; mi < 4; ++mi) a[nxt][mi] = pA[mi * 512 + (k + 1) * 4];
            #pragma unroll
            for (int ni = 0; ni < 4; ++ni) b[nxt][ni] = pB[ni * 512 + (k + 1) * 4];
        }
        #pragma unroll
        for (int mi = 0; mi < 4; ++mi)
            #pragma unroll
            for (int ni = 0; ni < 4; ++ni)
                acc[mi][ni] = __builtin_amdgcn_mfma_f32_16x16x32_bf16(a[cur][mi], b[cur][ni], acc[mi][ni], 0, 0, 0);
    }

    // ---- epilogue: different-class exp sums -> negsum (rows; cols via symmetry) ----
    int jcls[4];
    bool jval[4];
    #pragma unroll
    for (int ni = 0; ni < 4; ++ni) {
        int gcol = j0 + wc + ni * 16 + lr;
        jval[ni] = gcol < M_ROWS;
        unsigned tj = (unsigned)gcol / V_SEL;
        jcls[ni] = (int)(tj - (tj / NUM_REAL) * NUM_REAL);
    }
    float colacc[4] = {0.f, 0.f, 0.f, 0.f};
    #pragma unroll
    for (int mi = 0; mi < 4; ++mi) {
        #pragma unroll
        for (int reg = 0; reg < 4; ++reg) {
            int rloc = wr + mi * 16 + qr * 4 + reg;
            int grow = i0 + rloc;
            bool ival = grow < M_ROWS;
            unsigned ti = (unsigned)grow / V_SEL;
            int icls = (int)(ti - (ti / NUM_REAL) * NUM_REAL);
            float rowacc = 0.f;
            #pragma unroll
            for (int ni = 0; ni < 4; ++ni) {
                bool v = ival && jval[ni] && (icls != jcls[ni]);
                float e = v ? __expf(acc[mi][ni][reg] * 2.0f) : 0.f;
                rowacc += e;
                colacc[ni] += e;
            }
            rowacc += __shfl_xor(rowacc, 1, 64);
            rowacc += __shfl_xor(rowacc, 2, 64);
            rowacc += __shfl_xor(rowacc, 4, 64);
            rowacc += __shfl_xor(rowacc, 8, 64);
            if (lr == 0) red[rloc * 2 + (wave & 1)] = rowacc;
        }
    }
    #pragma unroll
    for (int ni = 0; ni < 4; ++ni) {
        float cc = colacc[ni];
        cc += __shfl_xor(cc, 16, 64);
        cc += __shfl_xor(cc, 32, 64);
        if (qr == 0) cred[(wc + ni * 16 + lr) * 2 + (wave >> 1)] = cc;
    }
    __syncthreads();
    if (tid < 128) {
        int row = i0 + tid;
        if (row < M_ROWS) atomicAdd(&negsum[row], red[tid * 2] + red[tid * 2 + 1]);
    } else {
        int cc2 = tid - 128, col = j0 + cc2;
        if (!diag && col < M_ROWS) atomicAdd(&negsum[col], cred[cc2 * 2] + cred[cc2 * 2 + 1]);
    }
}

// ---------------- Kernel 4: same-class Gram tiles -> positive loss terms ----------------
__global__ __launch_bounds__(256) void k_pos(const unsigned short* __restrict__ F,
                                             const float* __restrict__ negsum,
                                             float* __restrict__ out)
{
    __shared__ float wred[4];

    const int c = blockIdx.x / 15;
    int pidx = blockIdx.x % 15;
    int ti = 0;
    while (pidx >= CT - ti) { pidx -= CT - ti; ++ti; }
    const int tj = ti + pidx;
    const int u0i = ti * TILE, u0j = tj * TILE;
    const bool offd = (ti != tj);

    const int tid  = threadIdx.x;
    const int wave = tid >> 6, lane = tid & 63;
    const int qr = lane >> 4, lr = lane & 15;
    const int wr = (wave >> 1) * 64, wc = (wave & 1) * 64;

    floatx4 acc[4][4];
    floatx4 zero4 = {0.f, 0.f, 0.f, 0.f};
    #pragma unroll
    for (int a = 0; a < 4; ++a)
        #pragma unroll
        for (int b = 0; b < 4; ++b) acc[a][b] = zero4;

    auto growmap = [&](int u) -> int {
        int uc = u < 524 ? u : 523;
        int b = uc / 131, v = uc - 131 * b;
        return b * RPI + c * V_SEL + v;
    };
    const short8* pAm[4];
    const short8* pBn[4];
    #pragma unroll
    for (int mi = 0; mi < 4; ++mi)
        pAm[mi] = reinterpret_cast<const short8*>(F + (size_t)growmap(u0i + wr + mi * 16 + lr) * CDIM) + qr;
    #pragma unroll
    for (int ni = 0; ni < 4; ++ni)
        pBn[ni] = reinterpret_cast<const short8*>(F + (size_t)growmap(u0j + wc + ni * 16 + lr) * CDIM) + qr;

    short8 a[2][4], b[2][4];
    #pragma unroll
    for (int mi = 0; mi < 4; ++mi) a[0][mi] = pAm[mi][0];
    #pragma unroll
    for (int ni = 0; ni < 4; ++ni) b[0][ni] = pBn[ni][0];

    #pragma unroll
    for (int k = 0; k < 8; ++k) {
        const int cur = k & 1, nxt = cur ^ 1;
        if (k < 7) {
            #pragma unroll
            for (int mi = 0; mi < 4; ++mi) a[nxt][mi] = pAm[mi][(k + 1) * 4];
            #pragma unroll
            for (int ni = 0; ni < 4; ++ni) b[nxt][ni] = pBn[ni][(k + 1) * 4];
        }
        #pragma unroll
        for (int mi = 0; mi < 4; ++mi)
            #pragma unroll
            for (int ni = 0; ni < 4; ++ni)
                acc[mi][ni] = __builtin_amdgcn_mfma_f32_16x16x32_bf16(a[cur][mi], b[cur][ni], acc[mi][ni], 0, 0, 0);
    }

    int  ujv[4];
    bool jval[4];
    float nsj[4];
    #pragma unroll
    for (int ni = 0; ni < 4; ++ni) {
        int uj = u0j + wc + ni * 16 + lr;
        ujv[ni] = uj;
        jval[ni] = uj < 524;
        nsj[ni] = jval[ni] ? negsum[growmap(uj)] : 0.f;
    }
    float tsum = 0.f;
    #pragma unroll
    for (int mi = 0; mi < 4; ++mi) {
        #pragma unroll
        for (int reg = 0; reg < 4; ++reg) {
            int ui = u0i + wr + mi * 16 + qr * 4 + reg;
            bool ival = ui < 524;
            float nsi = ival ? negsum[growmap(ui)] : 0.f;
            #pragma unroll
            for (int ni = 0; ni < 4; ++ni) {
                if (ival && jval[ni] && ui != ujv[ni]) {
                    float l  = acc[mi][ni][reg] * 2.0f;
                    float el = __expf(l);
                    tsum += l - __logf(el + nsi);
                    if (offd) tsum += l - __logf(el + nsj[ni]);
                }
            }
        }
    }
    #pragma unroll
    for (int s = 32; s > 0; s >>= 1) tsum += __shfl_xor(tsum, s, 64);
    if (lane == 0) wred[wave] = tsum;
    __syncthreads();
    if (tid == 0) {
        const float scale = -1.0f / (523.0f * (float)M_ROWS);
        atomicAdd(out, (wred[0] + wred[1] + wred[2] + wred[3]) * scale);
    }
}

extern "C" void kernel_launch(void* const* d_in, const int* in_sizes, int n_in,
                              void* d_out, int out_size, void* d_ws, size_t ws_size,
                              hipStream_t stream)
{
    const int*   label = (const int*)d_in[0];
    const float* feats = (const float*)d_in[1];
    float*       out   = (float*)d_out;

    char* ws = (char*)d_ws;
    unsigned short* F = (unsigned short*)ws;                    // MP*CDIM*2 = 5,111,808 B
    size_t off = (size_t)MP * CDIM * 2;
    int* sel = (int*)(ws + off);
    off += (size_t)T_TOT * V_SEL * 4;
    off = (off + 255) & ~(size_t)255;
    float* negsum = (float*)(ws + off);                         // MP floats
    off += (size_t)MP * 4;
    float* nrm = (float*)(ws + off);                            // MP floats, contiguous w/ negsum
    off += (size_t)MP * 4;
    int* ghist = (int*)(ws + off);                              // 4*32*19 ints
    off += (size_t)NIMG * NCHUNK * NUM_REAL * 4;
    off = (off + 255) & ~(size_t)255;
    float* Ftmp = (float*)(ws + off);                           // MP*CDIM*4 ≈ 10.2 MB

    hipMemsetAsync(negsum, 0, (size_t)MP * 8, stream);          // negsum + nrm
    hipMemsetAsync(out, 0, sizeof(float), stream);

    dim3 gh(NCHUNK, NIMG);
    k_hist<<<gh, 256, 0, stream>>>(label, ghist);
    k_scatter<<<gh, 256, 0, stream>>>(label, ghist, sel);
    dim3 g1(CDIM / 4, NIMG);
    k_gather1<<<g1, 256, 0, stream>>>(feats, sel, Ftmp, nrm);
    k_gather2<<<MP / 4, 256, 0, stream>>>(Ftmp, nrm, F);
    k_gemm<<<NT1, 256, 0, stream>>>(F, negsum);
    k_pos<<<NT2, 256, 0, stream>>>(F, negsum, out);
}